// Round 6
// baseline (547.545 us; speedup 1.0000x reference)
//
#include <hip/hip_runtime.h>
#include <hip/hip_bf16.h>

// ---- types ----
typedef float f32x4 __attribute__((ext_vector_type(4)));
typedef short s16x8 __attribute__((ext_vector_type(8)));
typedef short s16x4 __attribute__((ext_vector_type(4)));

static __device__ __forceinline__ short f2bf(float f) {
  union { __hip_bfloat16 h; short s; } u;
  u.h = __float2bfloat16(f);
  return u.s;
}
static __device__ __forceinline__ unsigned pack2(float a, float b) {
  return ((unsigned)(unsigned short)f2bf(a)) | (((unsigned)(unsigned short)f2bf(b)) << 16);
}
static __device__ __forceinline__ s16x8 pack8(f32x4 v0, f32x4 v1) {
  s16x8 r;
  r[0] = f2bf(v0.x); r[1] = f2bf(v0.y); r[2] = f2bf(v0.z); r[3] = f2bf(v0.w);
  r[4] = f2bf(v1.x); r[5] = f2bf(v1.y); r[6] = f2bf(v1.z); r[7] = f2bf(v1.w);
  return r;
}

// ---- workspace layout (floats) ----
// Gram pipeline deleted: stats now come from y itself (computed in k_gemm).
#define STAT_SZ   (4 * 16 * 128 * 2)          // {sum, sumsq} per (s,b,o)
#define MEAN_BASE STAT_SZ
#define RSTD_BASE (MEAN_BASE + 4 * 16 * 128)

// ============================================================================
// K1: Y = W@X per (stage, b, n-tile of 128). Round-1 GEMM body (proven 116us,
//     VGPR 64 + 64-acc, 4 blocks/CU — round 5 proved bounds(256,5) spills).
//     Epilogue: store RAW y + accumulate per-o {sum, sumsq} partials
//     (16-lane in-register reduce -> 128 atomics/block; 350K atomics total,
//     30x fewer than the round-2 Gram fan-in that cost 90+ us).
// grid: 2736
// ============================================================================
__global__ __launch_bounds__(256, 3) void k_gemm(
    const float* __restrict__ x0, const float* __restrict__ x1,
    const float* __restrict__ x2, const float* __restrict__ x3,
    const float* __restrict__ x4,
    const float* __restrict__ l0, const float* __restrict__ l1,
    const float* __restrict__ l2, const float* __restrict__ l3,
    const float* __restrict__ l4,
    float* __restrict__ stat, float* __restrict__ out) {
  const int bid = blockIdx.x;
  int s, b, nt; const float *xp, *lp; int N; long long ooff;
  if (bid < 2048)      { s = 0; b = bid >> 7;            nt = bid & 127;     xp = x0; lp = l0; N = 16384; ooff = 0; }
  else if (bid < 2560) { int r = bid - 2048; s = 1; b = r >> 5; nt = r & 31; xp = x1; lp = l1; N = 4096;  ooff = 33554432LL; }
  else if (bid < 2688) { int r = bid - 2560; s = 2; b = r >> 3; nt = r & 7;  xp = x2; lp = l2; N = 1024;  ooff = 41943040LL; }
  else if (bid < 2720) { int r = bid - 2688; s = 3; b = r >> 1; nt = r & 1;  xp = x3; lp = l3; N = 256;   ooff = 44040192LL; }
  else                 { int r = bid - 2720; s = 4; b = r;      nt = 0;      xp = x4; lp = l4; N = 64;    ooff = 44564480LL; }
  const int t = threadIdx.x;
  const int lane = t & 63, wv = t >> 6;

  __shared__ short Xt[128 * 136];   // [n][c] bf16, row stride 136 shorts (272B)

  // ---- stage Xt: coalesced loads (4 rows x 256B per instr), register 4x4
  //      transpose across lane groups of 4, single b64 LDS write per f32x4 ----
  {
    const int g = lane >> 2, q4 = lane & 3;
    const float* xg = xp + (long long)b * 128 * N + (long long)nt * 128;
    #pragma unroll
    for (int j = 0; j < 16; ++j) {
      const int cb = (j & 7) * 16 + wv * 4;          // 4-row block base
      const int c  = cb + q4;
      const int n0 = (j >> 3) * 64 + g * 4;          // 4-col block base
      f32x4 v = {0.f, 0.f, 0.f, 0.f};
      if (nt * 128 + n0 + 3 < N)                     // wave-uniform guard
        v = *(const f32x4*)(xg + (long long)c * N + n0);
      unsigned u01 = pack2(v.x, v.y);
      unsigned u23 = pack2(v.z, v.w);
      unsigned p01 = __shfl_xor(u01, 1, 64);
      unsigned p23 = __shfl_xor(u23, 1, 64);
      unsigned t01 = (q4 & 1) ? ((p01 >> 16) | (u01 & 0xffff0000u))
                              : ((u01 & 0xffffu) | (p01 << 16));
      unsigned t23 = (q4 & 1) ? ((p23 >> 16) | (u23 & 0xffff0000u))
                              : ((u23 & 0xffffu) | (p23 << 16));
      unsigned s01 = __shfl_xor(t01, 2, 64);
      unsigned s23 = __shfl_xor(t23, 2, 64);
      unsigned lo = (q4 & 2) ? s23 : t01;
      unsigned hi = (q4 & 2) ? t23 : s01;
      const int n = n0 + q4;
      *(unsigned long long*)&Xt[n * 136 + cb] =
          ((unsigned long long)hi << 32) | (unsigned long long)lo;
    }
  }
  __syncthreads();

  const int wm = wv >> 1, wn = wv & 1;
  const int l15 = lane & 15, quad = lane >> 4;
  const float* wg = lp + (long long)b * 16384;
  f32x4 acc[4][4];
  #pragma unroll
  for (int i = 0; i < 4; ++i)
    #pragma unroll
    for (int j = 0; j < 4; ++j) { f32x4 z = {0.f,0.f,0.f,0.f}; acc[i][j] = z; }

  #pragma unroll
  for (int kk = 0; kk < 4; ++kk) {              // c0 = kk*32
    s16x8 af[4], bfq[4];
    #pragma unroll
    for (int i = 0; i < 4; ++i) {
      const int m = wm * 64 + i * 16 + l15;
      f32x4 w0 = *(const f32x4*)(wg + m * 128 + kk * 32 + quad * 8);
      f32x4 w1 = *(const f32x4*)(wg + m * 128 + kk * 32 + quad * 8 + 4);
      af[i] = pack8(w0, w1);
    }
    #pragma unroll
    for (int j = 0; j < 4; ++j) {
      const int n = wn * 64 + j * 16 + l15;
      bfq[j] = *(const s16x8*)&Xt[n * 136 + kk * 32 + quad * 8];
    }
    #pragma unroll
    for (int i = 0; i < 4; ++i)
      #pragma unroll
      for (int j = 0; j < 4; ++j)
        acc[i][j] = __builtin_amdgcn_mfma_f32_16x16x32_bf16(af[i], bfq[j], acc[i][j], 0, 0, 0);
  }

  // ---- per-o {sum, sumsq} partials (stages 0-3 only; full 128-n tiles) ----
  if (s < 4) {
    float* ST = stat + (long long)(s * 16 + b) * 256;
    #pragma unroll
    for (int i = 0; i < 4; ++i) {
      #pragma unroll
      for (int rr = 0; rr < 4; ++rr) {
        float sv = 0.f, sq = 0.f;
        #pragma unroll
        for (int j = 0; j < 4; ++j) {
          const float v = acc[i][j][rr];
          sv += v; sq += v * v;
        }
        #pragma unroll
        for (int off = 1; off < 16; off <<= 1) {   // reduce over l15 group
          sv += __shfl_xor(sv, off, 64);
          sq += __shfl_xor(sq, off, 64);
        }
        if (l15 == 0) {
          const int o = wm * 64 + i * 16 + quad * 4 + rr;
          unsafeAtomicAdd(&ST[o * 2],     sv);
          unsafeAtomicAdd(&ST[o * 2 + 1], sq);
        }
      }
    }
  }

  // ---- store raw y (normalization happens in k_norm) ----
  #pragma unroll
  for (int i = 0; i < 4; ++i) {
    #pragma unroll
    for (int rr = 0; rr < 4; ++rr) {
      const int o = wm * 64 + i * 16 + quad * 4 + rr;
      float* orow = out + ooff + (long long)(b * 128 + o) * N + (long long)nt * 128;
      #pragma unroll
      for (int j = 0; j < 4; ++j) {
        const int n = wn * 64 + j * 16 + l15;
        if (nt * 128 + n < N) orow[n] = acc[i][j][rr];
      }
    }
  }
}

// ============================================================================
// K2: mean/rstd from the 8192 {sum,sumsq} pairs.  grid: 32
// ============================================================================
__global__ __launch_bounds__(256) void k_final(
    const float* __restrict__ stat, float* __restrict__ meanw,
    float* __restrict__ rstdw) {
  const int idx = blockIdx.x * 256 + threadIdx.x;    // 0..8191 = s*2048+b*128+o
  const int s = idx >> 11;
  const float Ninv = (s == 0) ? (1.f/16384.f) : (s == 1) ? (1.f/4096.f)
                   : (s == 2) ? (1.f/1024.f) : (1.f/256.f);
  const float sv = stat[idx * 2], sq = stat[idx * 2 + 1];
  const float mean = sv * Ninv;
  const float var  = sq * Ninv - mean * mean;
  meanw[idx] = mean;
  rstdw[idx] = rsqrtf(var + 1e-5f);
}

// ============================================================================
// K3: in-place streaming normalize of stages 0-3 (first 44564480 floats of
//     out). Element-wise in-place: race-free. Pure BW: ~356 MB round trip.
// grid: 2048
// ============================================================================
__global__ __launch_bounds__(256) void k_norm(
    const float* __restrict__ meanw, const float* __restrict__ rstdw,
    float* __restrict__ out) {
  const long long V = 11141120LL;                    // 44564480 / 4
  const long long stride = (long long)gridDim.x * 256;
  for (long long v = (long long)blockIdx.x * 256 + threadIdx.x; v < V; v += stride) {
    const long long e = v << 2;
    int mi;
    if (e < 33554432LL)      mi =        (int)(e >> 14);
    else if (e < 41943040LL) mi = 2048 + (int)((e - 33554432LL) >> 12);
    else if (e < 44040192LL) mi = 4096 + (int)((e - 41943040LL) >> 10);
    else                     mi = 6144 + (int)((e - 44040192LL) >> 8);
    const float mean = meanw[mi], rstd = rstdw[mi];
    f32x4 y = *(const f32x4*)(out + e);
    y.x = (y.x - mean) * rstd;
    y.y = (y.y - mean) * rstd;
    y.z = (y.z - mean) * rstd;
    y.w = (y.w - mean) * rstd;
    *(f32x4*)(out + e) = y;
  }
}

extern "C" void kernel_launch(void* const* d_in, const int* in_sizes, int n_in,
                              void* d_out, int out_size, void* d_ws, size_t ws_size,
                              hipStream_t stream) {
  // dict order: x1,l1fs,x2,l2fs,x3,l3fs,x4,l4fs,x5,l5fs
  const float* x[5] = {(const float*)d_in[0], (const float*)d_in[2], (const float*)d_in[4],
                       (const float*)d_in[6], (const float*)d_in[8]};
  const float* l[5] = {(const float*)d_in[1], (const float*)d_in[3], (const float*)d_in[5],
                       (const float*)d_in[7], (const float*)d_in[9]};
  float* ws  = (float*)d_ws;
  float* out = (float*)d_out;

  // zero the {sum,sumsq} accumulator (64 KB; ws is poisoned each launch)
  hipMemsetAsync(d_ws, 0, (size_t)STAT_SZ * sizeof(float), stream);

  k_gemm <<<2736, 256, 0, stream>>>(x[0], x[1], x[2], x[3], x[4],
                                    l[0], l[1], l[2], l[3], l[4],
                                    ws, out);
  k_final<<<32,   256, 0, stream>>>(ws, ws + MEAN_BASE, ws + RSTD_BASE);
  k_norm <<<2048, 256, 0, stream>>>(ws + MEAN_BASE, ws + RSTD_BASE, out);
}

// Round 7
// 466.642 us; speedup vs baseline: 1.1734x; 1.1734x over previous
//
#include <hip/hip_runtime.h>
#include <hip/hip_bf16.h>

// ---- types ----
typedef float f32x4 __attribute__((ext_vector_type(4)));
typedef short s16x8 __attribute__((ext_vector_type(8)));
typedef short s16x4 __attribute__((ext_vector_type(4)));

static __device__ __forceinline__ short f2bf(float f) {
  union { __hip_bfloat16 h; short s; } u;
  u.h = __float2bfloat16(f);
  return u.s;
}
static __device__ __forceinline__ unsigned pack2(float a, float b) {
  return ((unsigned)(unsigned short)f2bf(a)) | (((unsigned)(unsigned short)f2bf(b)) << 16);
}
static __device__ __forceinline__ s16x8 pack8(f32x4 v0, f32x4 v1) {
  s16x8 r;
  r[0] = f2bf(v0.x); r[1] = f2bf(v0.y); r[2] = f2bf(v0.z); r[3] = f2bf(v0.w);
  r[4] = f2bf(v1.x); r[5] = f2bf(v1.y); r[6] = f2bf(v1.z); r[7] = f2bf(v1.w);
  return r;
}

// ---- workspace layout (floats) ----
#define MEAN_BASE 0
#define RSTD_BASE 8192
#define STAT_BASE 16384                      // atomic-fallback {sum,sq}, 16384 floats
#define PART_BASE 32768                      // per-block partials, 2736*512 floats
#define PART_SZ   (2736 * 512)

// ============================================================================
// K1: Y = W@X per (stage, b, n-tile of 128). Round-1 GEMM body (proven 116us).
//     Epilogue: store RAW y + per-o {sum,sq} partials to a PRIVATE 2KB slot
//     (plain stores — round 6 proved 1.4M contended atomics cost ~190us;
//     round 4 proved private-partials+reduce is free).
// grid: 2736
// ============================================================================
__global__ __launch_bounds__(256, 3) void k_gemm(
    const float* __restrict__ x0, const float* __restrict__ x1,
    const float* __restrict__ x2, const float* __restrict__ x3,
    const float* __restrict__ x4,
    const float* __restrict__ l0, const float* __restrict__ l1,
    const float* __restrict__ l2, const float* __restrict__ l3,
    const float* __restrict__ l4,
    float* __restrict__ part, float* __restrict__ stat, const int use_part,
    float* __restrict__ out) {
  const int bid = blockIdx.x;
  int s, b, nt; const float *xp, *lp; int N; long long ooff;
  if (bid < 2048)      { s = 0; b = bid >> 7;            nt = bid & 127;     xp = x0; lp = l0; N = 16384; ooff = 0; }
  else if (bid < 2560) { int r = bid - 2048; s = 1; b = r >> 5; nt = r & 31; xp = x1; lp = l1; N = 4096;  ooff = 33554432LL; }
  else if (bid < 2688) { int r = bid - 2560; s = 2; b = r >> 3; nt = r & 7;  xp = x2; lp = l2; N = 1024;  ooff = 41943040LL; }
  else if (bid < 2720) { int r = bid - 2688; s = 3; b = r >> 1; nt = r & 1;  xp = x3; lp = l3; N = 256;   ooff = 44040192LL; }
  else                 { int r = bid - 2720; s = 4; b = r;      nt = 0;      xp = x4; lp = l4; N = 64;    ooff = 44564480LL; }
  const int t = threadIdx.x;
  const int lane = t & 63, wv = t >> 6;

  __shared__ short Xt[128 * 136];   // [n][c] bf16, row stride 136 shorts (272B)

  // ---- stage Xt: coalesced loads (4 rows x 256B per instr), register 4x4
  //      transpose across lane groups of 4, single b64 LDS write per f32x4 ----
  {
    const int g = lane >> 2, q4 = lane & 3;
    const float* xg = xp + (long long)b * 128 * N + (long long)nt * 128;
    #pragma unroll
    for (int j = 0; j < 16; ++j) {
      const int cb = (j & 7) * 16 + wv * 4;          // 4-row block base
      const int c  = cb + q4;
      const int n0 = (j >> 3) * 64 + g * 4;          // 4-col block base
      f32x4 v = {0.f, 0.f, 0.f, 0.f};
      if (nt * 128 + n0 + 3 < N)                     // wave-uniform guard
        v = *(const f32x4*)(xg + (long long)c * N + n0);
      unsigned u01 = pack2(v.x, v.y);
      unsigned u23 = pack2(v.z, v.w);
      unsigned p01 = __shfl_xor(u01, 1, 64);
      unsigned p23 = __shfl_xor(u23, 1, 64);
      unsigned t01 = (q4 & 1) ? ((p01 >> 16) | (u01 & 0xffff0000u))
                              : ((u01 & 0xffffu) | (p01 << 16));
      unsigned t23 = (q4 & 1) ? ((p23 >> 16) | (u23 & 0xffff0000u))
                              : ((u23 & 0xffffu) | (p23 << 16));
      unsigned s01 = __shfl_xor(t01, 2, 64);
      unsigned s23 = __shfl_xor(t23, 2, 64);
      unsigned lo = (q4 & 2) ? s23 : t01;
      unsigned hi = (q4 & 2) ? t23 : s01;
      const int n = n0 + q4;
      *(unsigned long long*)&Xt[n * 136 + cb] =
          ((unsigned long long)hi << 32) | (unsigned long long)lo;
    }
  }
  __syncthreads();

  const int wm = wv >> 1, wn = wv & 1;
  const int l15 = lane & 15, quad = lane >> 4;
  const float* wg = lp + (long long)b * 16384;
  f32x4 acc[4][4];
  #pragma unroll
  for (int i = 0; i < 4; ++i)
    #pragma unroll
    for (int j = 0; j < 4; ++j) { f32x4 z = {0.f,0.f,0.f,0.f}; acc[i][j] = z; }

  #pragma unroll
  for (int kk = 0; kk < 4; ++kk) {              // c0 = kk*32
    s16x8 af[4], bfq[4];
    #pragma unroll
    for (int i = 0; i < 4; ++i) {
      const int m = wm * 64 + i * 16 + l15;
      f32x4 w0 = *(const f32x4*)(wg + m * 128 + kk * 32 + quad * 8);
      f32x4 w1 = *(const f32x4*)(wg + m * 128 + kk * 32 + quad * 8 + 4);
      af[i] = pack8(w0, w1);
    }
    #pragma unroll
    for (int j = 0; j < 4; ++j) {
      const int n = wn * 64 + j * 16 + l15;
      bfq[j] = *(const s16x8*)&Xt[n * 136 + kk * 32 + quad * 8];
    }
    #pragma unroll
    for (int i = 0; i < 4; ++i)
      #pragma unroll
      for (int j = 0; j < 4; ++j)
        acc[i][j] = __builtin_amdgcn_mfma_f32_16x16x32_bf16(af[i], bfq[j], acc[i][j], 0, 0, 0);
  }

  // ---- per-o {sum, sq}: 16-lane reduce, then PRIVATE plain stores ----
  if (s < 4) {
    float* P = part + (long long)bid * 512;
    float* ST = stat + (long long)(s * 16 + b) * 256;
    #pragma unroll
    for (int i = 0; i < 4; ++i) {
      #pragma unroll
      for (int rr = 0; rr < 4; ++rr) {
        float sv = 0.f, sq = 0.f;
        #pragma unroll
        for (int j = 0; j < 4; ++j) {
          const float v = acc[i][j][rr];
          sv += v; sq += v * v;
        }
        #pragma unroll
        for (int off = 1; off < 16; off <<= 1) {   // reduce over l15 group
          sv += __shfl_xor(sv, off, 64);
          sq += __shfl_xor(sq, off, 64);
        }
        if (l15 == 0) {
          const int o = wm * 64 + i * 16 + quad * 4 + rr;
          if (use_part) {
            P[(wn * 128 + o) * 2]     = sv;
            P[(wn * 128 + o) * 2 + 1] = sq;
          } else {
            unsafeAtomicAdd(&ST[o * 2],     sv);
            unsafeAtomicAdd(&ST[o * 2 + 1], sq);
          }
        }
      }
    }
  }

  // ---- store raw y (normalization happens in k_norm) ----
  #pragma unroll
  for (int i = 0; i < 4; ++i) {
    #pragma unroll
    for (int rr = 0; rr < 4; ++rr) {
      const int o = wm * 64 + i * 16 + quad * 4 + rr;
      float* orow = out + ooff + (long long)(b * 128 + o) * N + (long long)nt * 128;
      #pragma unroll
      for (int j = 0; j < 4; ++j) {
        const int n = wn * 64 + j * 16 + l15;
        if (nt * 128 + n < N) orow[n] = acc[i][j][rr];
      }
    }
  }
}

// ============================================================================
// K2: reduce per-block partials -> mean/rstd per (s,b,o).  grid: 64
//     Block = (s,b); lanes o=t&127 coalesced over the 512-float slots.
// ============================================================================
__global__ __launch_bounds__(256) void k_final(
    const float* __restrict__ part, const float* __restrict__ stat,
    const int use_part, float* __restrict__ meanw, float* __restrict__ rstdw) {
  const int bid = blockIdx.x;
  const int s = bid >> 4, b = bid & 15;
  int start, kc;
  if (s == 0)      { start = b * 128;        kc = 128; }
  else if (s == 1) { start = 2048 + b * 32;  kc = 32; }
  else if (s == 2) { start = 2560 + b * 8;   kc = 8; }
  else             { start = 2688 + b * 2;   kc = 2; }
  const float Ninv = (s == 0) ? (1.f/16384.f) : (s == 1) ? (1.f/4096.f)
                   : (s == 2) ? (1.f/1024.f) : (1.f/256.f);
  const int t = threadIdx.x;
  const int o = t & 127, h = t >> 7;

  __shared__ float r0[256], r1[256];
  float sv = 0.f, sq = 0.f;
  if (use_part) {
    for (int nt = h; nt < kc; nt += 2) {
      const float* pp = part + (long long)(start + nt) * 512 + o * 2;
      sv += pp[0] + pp[256];
      sq += pp[1] + pp[257];
    }
  } else if (h == 0) {
    const float* ST = stat + (long long)(s * 16 + b) * 256;
    sv = ST[o * 2]; sq = ST[o * 2 + 1];
  }
  r0[t] = sv; r1[t] = sq;
  __syncthreads();
  if (h == 0) {
    sv = r0[t] + r0[t + 128];
    sq = r1[t] + r1[t + 128];
    if (!use_part) { sv = r0[t]; sq = r1[t]; }
    const float mean = sv * Ninv;
    const float var  = sq * Ninv - mean * mean;
    const int idx = (s * 16 + b) * 128 + o;
    meanw[idx] = mean;
    rstdw[idx] = rsqrtf(var + 1e-5f);
  }
}

// ============================================================================
// K3: in-place streaming normalize of stages 0-3 (first 44564480 floats of
//     out). Element-wise in-place: race-free. Pure BW: ~356 MB round trip.
// grid: 2048
// ============================================================================
__global__ __launch_bounds__(256) void k_norm(
    const float* __restrict__ meanw, const float* __restrict__ rstdw,
    float* __restrict__ out) {
  const long long V = 11141120LL;                    // 44564480 / 4
  const long long stride = (long long)gridDim.x * 256;
  for (long long v = (long long)blockIdx.x * 256 + threadIdx.x; v < V; v += stride) {
    const long long e = v << 2;
    int mi;
    if (e < 33554432LL)      mi =        (int)(e >> 14);
    else if (e < 41943040LL) mi = 2048 + (int)((e - 33554432LL) >> 12);
    else if (e < 44040192LL) mi = 4096 + (int)((e - 41943040LL) >> 10);
    else                     mi = 6144 + (int)((e - 44040192LL) >> 8);
    const float mean = meanw[mi], rstd = rstdw[mi];
    f32x4 y = *(const f32x4*)(out + e);
    y.x = (y.x - mean) * rstd;
    y.y = (y.y - mean) * rstd;
    y.z = (y.z - mean) * rstd;
    y.w = (y.w - mean) * rstd;
    *(f32x4*)(out + e) = y;
  }
}

extern "C" void kernel_launch(void* const* d_in, const int* in_sizes, int n_in,
                              void* d_out, int out_size, void* d_ws, size_t ws_size,
                              hipStream_t stream) {
  // dict order: x1,l1fs,x2,l2fs,x3,l3fs,x4,l4fs,x5,l5fs
  const float* x[5] = {(const float*)d_in[0], (const float*)d_in[2], (const float*)d_in[4],
                       (const float*)d_in[6], (const float*)d_in[8]};
  const float* l[5] = {(const float*)d_in[1], (const float*)d_in[3], (const float*)d_in[5],
                       (const float*)d_in[7], (const float*)d_in[9]};
  float* ws  = (float*)d_ws;
  float* out = (float*)d_out;

  // Partials need 5.7 MB of ws; prior rounds used 4.3 MB successfully.
  // Fallback to the (slow but correct) atomic path if ws is smaller.
  const int use_part =
      ws_size >= (size_t)(PART_BASE + PART_SZ) * sizeof(float) ? 1 : 0;
  if (!use_part)
    hipMemsetAsync((char*)d_ws + (size_t)STAT_BASE * sizeof(float), 0,
                   16384 * sizeof(float), stream);

  k_gemm <<<2736, 256, 0, stream>>>(x[0], x[1], x[2], x[3], x[4],
                                    l[0], l[1], l[2], l[3], l[4],
                                    ws + PART_BASE, ws + STAT_BASE, use_part,
                                    out);
  k_final<<<64,   256, 0, stream>>>(ws + PART_BASE, ws + STAT_BASE, use_part,
                                    ws + MEAN_BASE, ws + RSTD_BASE);
  k_norm <<<2048, 256, 0, stream>>>(ws + MEAN_BASE, ws + RSTD_BASE, out);
}